// Round 1
// baseline (559.785 us; speedup 1.0000x reference)
//
#include <hip/hip_runtime.h>

// MLP_RSNA6: B=500000 rows of 200 fp32. 25 groups x 8 contiguous inputs ->
// dot(w1)+b1 -> relu -> scalar h -> 3 outputs h*w2[t]+b2[t] into 3 contiguous
// output cols. out = (B, 75) fp32.
//
// Memory-bound: 400 MB read + 150 MB write = 550 MB min -> ~87 us @ 6.3 TB/s.
// One thread per (b,g): 2x float4 load (32B, aligned since base = b*200+g*8),
// 3 dword stores (globally contiguous stream). Group base indices are read
// from in_out_k/in_out_v (always arange in this problem; contiguity within a
// group is exploited for vector loads).

#define GROUPS  25
#define IN_NUM  8
#define ROW     200
#define OUTROW  75
#define OUTT    3

__global__ __launch_bounds__(256) void mlp_rsna6_kernel(
    const float* __restrict__ x,
    const float* __restrict__ w1,
    const float* __restrict__ b1,
    const float* __restrict__ w2,
    const float* __restrict__ b2,
    const int*   __restrict__ iok,
    const int*   __restrict__ iov,
    float*       __restrict__ out,
    int total)   // B * GROUPS
{
    int t = blockIdx.x * blockDim.x + threadIdx.x;
    if (t >= total) return;

    int b = t / GROUPS;          // compiler emits magic-mul for /25
    int g = t - b * GROUPS;

    // Base indices for this group (arange => kbase = g*8, vbase = g*3).
    int kbase = iok[g * IN_NUM];
    int vbase = iov[g * OUTT];

    const float4* xp = reinterpret_cast<const float4*>(
        x + (size_t)b * ROW + kbase);
    float4 a0 = xp[0];
    float4 a1 = xp[1];

    // Weights: uniform addresses -> scalar loads, L1/SGPR broadcast.
    float s = b1[0];
    s = fmaf(a0.x, w1[0], s);
    s = fmaf(a0.y, w1[1], s);
    s = fmaf(a0.z, w1[2], s);
    s = fmaf(a0.w, w1[3], s);
    s = fmaf(a1.x, w1[4], s);
    s = fmaf(a1.y, w1[5], s);
    s = fmaf(a1.z, w1[6], s);
    s = fmaf(a1.w, w1[7], s);
    float h = fmaxf(s, 0.0f);

    float* op = out + (size_t)b * OUTROW + vbase;
    op[0] = fmaf(h, w2[0], b2[0]);
    op[1] = fmaf(h, w2[1], b2[1]);
    op[2] = fmaf(h, w2[2], b2[2]);
}

extern "C" void kernel_launch(void* const* d_in, const int* in_sizes, int n_in,
                              void* d_out, int out_size, void* d_ws, size_t ws_size,
                              hipStream_t stream) {
    const float* x   = (const float*)d_in[0];
    const float* w1  = (const float*)d_in[1];
    const float* b1  = (const float*)d_in[2];
    const float* w2  = (const float*)d_in[3];
    const float* b2  = (const float*)d_in[4];
    const int*   iok = (const int*)d_in[5];
    const int*   iov = (const int*)d_in[6];
    float*       out = (float*)d_out;

    int B = in_sizes[0] / ROW;          // 500000
    int total = B * GROUPS;             // 12.5M threads

    int block = 256;
    int grid = (total + block - 1) / block;
    mlp_rsna6_kernel<<<grid, block, 0, stream>>>(
        x, w1, b1, w2, b2, iok, iov, out, total);
}